// Round 1
// baseline (643.641 us; speedup 1.0000x reference)
//
#include <hip/hip_runtime.h>
#include <stdint.h>
#include <stddef.h>

// Problem: out[65536,1024] = X[65536,1024] . W0[1024,1024]^T + b0   (all fp32)
// Strategy: convert W0 -> bf16 once into d_ws (2 MB); single bf16-MFMA GEMM
// kernel stages A (X) with fused fp32->bf16 conversion through VGPRs, and
// B (W0 bf16) via async global_load_lds (16B) into a double-buffered LDS tile.
// XOR-swizzled 16B k-groups kill the ds_read_b128 bank conflicts.

#define BATCH   65536
#define HIDDEN  1024
#define BM      128
#define BN      128
#define BK      32
#define KTILES  (HIDDEN / BK)   // 32

typedef __bf16 bf16;
typedef __attribute__((ext_vector_type(8))) __bf16 bf16x8;
typedef __attribute__((ext_vector_type(4))) __bf16 bf16x4;
typedef __attribute__((ext_vector_type(4))) float  f32x4;

__device__ __forceinline__ void async_ld16(const bf16* g, bf16* l) {
    __builtin_amdgcn_global_load_lds(
        (const __attribute__((address_space(1))) uint32_t*)g,
        (__attribute__((address_space(3))) uint32_t*)l,
        16, 0, 0);
}

__device__ __forceinline__ bf16x8 cvt8(f32x4 a, f32x4 b) {
    bf16x8 r;
    r[0] = (bf16)a[0]; r[1] = (bf16)a[1]; r[2] = (bf16)a[2]; r[3] = (bf16)a[3];
    r[4] = (bf16)b[0]; r[5] = (bf16)b[1]; r[6] = (bf16)b[2]; r[7] = (bf16)b[3];
    return r;
}

// W0 (1024x1024 fp32) -> bf16 into workspace. 1024 blocks x 256 thr x 4 elems.
__global__ void convert_w_kernel(const float* __restrict__ W, bf16* __restrict__ Wb) {
    int i = (blockIdx.x * 256 + threadIdx.x) * 4;
    f32x4 v = *(const f32x4*)(W + i);
    bf16x4 o;
    o[0] = (bf16)v[0]; o[1] = (bf16)v[1]; o[2] = (bf16)v[2]; o[3] = (bf16)v[3];
    *(bf16x4*)(Wb + i) = o;
}

__global__ __launch_bounds__(256, 3)
void moa_gemm_kernel(const float* __restrict__ X, const bf16* __restrict__ Wb,
                     const float* __restrict__ bias, float* __restrict__ out) {
    // LDS: A tile [128 rows][32 k] bf16 (8 KB), B tile double-buffered (2x8 KB).
    // Rows are 64 B; the four 16 B k-groups of row r are stored at slot
    // g' = g ^ (r&3) ^ ((r>>2)&3)  (applied as a gather permutation on the
    // global side so global_load_lds's linear lane->LDS mapping still works).
    __shared__ bf16 Asm[BM * BK];
    __shared__ bf16 Bsm[2][BN * BK];

    const int tid  = threadIdx.x;
    const int wave = tid >> 6;
    const int lane = tid & 63;
    const int tileM = blockIdx.y * BM;
    const int tileN = blockIdx.x * BN;

    // ---- A staging map: thread t fills linear LDS 16B-slots t and t+256 ----
    const int ar = tid >> 2;                                   // LDS row 0..63 (+64)
    const int ag = (tid & 3) ^ (ar & 3) ^ ((ar >> 2) & 3);     // swizzled global k-group
    const float* aP0 = X + (size_t)(tileM + ar) * HIDDEN + ag * 8;
    const float* aP1 = aP0 + (size_t)64 * HIDDEN;

    // ---- B staging map: wave w, chunk j in {0,1}: 16 rows per async block ----
    const int br = lane >> 2;                                  // row within 16-row block
    const int bg = (lane & 3) ^ (br & 3) ^ ((br >> 2) & 3);
    const bf16* bP = Wb + (size_t)(tileN + wave * 32 + br) * HIDDEN + bg * 8;

    // ---- fragment read map (16x16x32 bf16) ----
    const int frow = lane & 15;
    const int fq   = lane >> 4;
    const int fko  = (fq ^ (frow & 3) ^ ((frow >> 2) & 3)) * 8; // swizzled k offset
    const int waveM = (wave >> 1) * 64;
    const int waveN = (wave & 1) * 64;

    f32x4 acc[4][4];
    #pragma unroll
    for (int i = 0; i < 4; ++i)
        #pragma unroll
        for (int j = 0; j < 4; ++j) acc[i][j] = f32x4{0.f, 0.f, 0.f, 0.f};

    // Prologue: prefetch A[0] into regs, issue async B[0] into buffer 0.
    f32x4 apf0 = ((const f32x4*)aP0)[0];
    f32x4 apf1 = ((const f32x4*)aP0)[1];
    f32x4 apf2 = ((const f32x4*)aP1)[0];
    f32x4 apf3 = ((const f32x4*)aP1)[1];
    async_ld16(bP,               &Bsm[0][wave * 1024]);
    async_ld16(bP + 16 * HIDDEN, &Bsm[0][wave * 1024 + 512]);

    for (int kt = 0; kt < KTILES; ++kt) {
        // Convert this chunk's A registers (loaded one iteration ago).
        bf16x8 w0 = cvt8(apf0, apf1);
        bf16x8 w1 = cvt8(apf2, apf3);
        __syncthreads();                                   // (a) prev readers done
        *(bf16x8*)(&Asm[tid * 8])        = w0;             // linear -> conflict-free
        *(bf16x8*)(&Asm[2048 + tid * 8]) = w1;
        __syncthreads();                                   // (b) A + B[kt] visible

        const int nkt = kt + 1;
        if (nkt < KTILES) {
            // A[k+1] -> regs (latency hidden behind this chunk's MFMAs)
            const f32x4* s0 = (const f32x4*)(aP0 + nkt * BK);
            const f32x4* s1 = (const f32x4*)(aP1 + nkt * BK);
            apf0 = s0[0]; apf1 = s0[1];
            apf2 = s1[0]; apf3 = s1[1];
            // B[k+1] -> other LDS buffer (drained only at next iter's barrier (b))
            const bf16* bsrc = bP + nkt * BK;
            bf16* bdst = &Bsm[nkt & 1][wave * 1024];
            async_ld16(bsrc,               bdst);
            async_ld16(bsrc + 16 * HIDDEN, bdst + 512);
        }

        const bf16* Ab = &Asm[(waveM + frow) * BK + fko];
        const bf16* Bb = &Bsm[kt & 1][(waveN + frow) * BK + fko];
        bf16x8 aF[4], bF[4];
        #pragma unroll
        for (int mi = 0; mi < 4; ++mi) aF[mi] = *(const bf16x8*)(Ab + mi * 16 * BK);
        #pragma unroll
        for (int ni = 0; ni < 4; ++ni) bF[ni] = *(const bf16x8*)(Bb + ni * 16 * BK);
        #pragma unroll
        for (int mi = 0; mi < 4; ++mi)
            #pragma unroll
            for (int ni = 0; ni < 4; ++ni)
                acc[mi][ni] = __builtin_amdgcn_mfma_f32_16x16x32_bf16(
                    aF[mi], bF[ni], acc[mi][ni], 0, 0, 0);
    }

    // Epilogue: C/D layout col=lane&15, row=(lane>>4)*4+r (m89-verified).
    const int orow0 = tileM + waveM + (lane >> 4) * 4;
    const int ocol0 = tileN + waveN + (lane & 15);
    float bv[4];
    #pragma unroll
    for (int ni = 0; ni < 4; ++ni) bv[ni] = bias[ocol0 + ni * 16];
    #pragma unroll
    for (int mi = 0; mi < 4; ++mi) {
        #pragma unroll
        for (int r = 0; r < 4; ++r) {
            float* orow = out + (size_t)(orow0 + mi * 16 + r) * HIDDEN;
            #pragma unroll
            for (int ni = 0; ni < 4; ++ni)
                orow[ocol0 + ni * 16] = acc[mi][ni][r] + bv[ni];
        }
    }
}

extern "C" void kernel_launch(void* const* d_in, const int* in_sizes, int n_in,
                              void* d_out, int out_size, void* d_ws, size_t ws_size,
                              hipStream_t stream) {
    const float* x  = (const float*)d_in[0];
    // d_in[1] = routing_vectors: unused (reference overwrites routing with adaptor 0)
    const float* W  = (const float*)d_in[2];   // [8,1024,1024]; adaptor 0 = first 1M
    const float* b  = (const float*)d_in[3];   // [8,1024]; adaptor 0 = first 1024
    float* out      = (float*)d_out;
    bf16*  Wb       = (bf16*)d_ws;             // needs 2 MB of workspace

    convert_w_kernel<<<dim3(HIDDEN * HIDDEN / (256 * 4)), dim3(256), 0, stream>>>(W, Wb);

    // x-fastest over column tiles so the 8 blocks sharing an X panel are
    // co-resident (panel read from HBM once, rest via L3; W0 bf16 fits in L2).
    dim3 grid(HIDDEN / BN, BATCH / BM);
    moa_gemm_kernel<<<grid, dim3(256), 0, stream>>>(x, Wb, b, out);
}

// Round 2
// 594.900 us; speedup vs baseline: 1.0819x; 1.0819x over previous
//
#include <hip/hip_runtime.h>
#include <stdint.h>
#include <stddef.h>

// out[65536,1024] = X . W0^T + b0 (fp32 in/out), computed via bf16 MFMA.
// R2: (1) XCD-aware block remap so the 8 blocks sharing an X row-panel land on
// the SAME XCD's L2 in lockstep (R1 showed 4x X over-fetch: FETCH 1.05 GB);
// (2) double-buffered A+B LDS -> single __syncthreads per K-iter (halve the
// vmcnt(0) barrier drains).

#define BATCH   65536
#define HIDDEN  1024
#define BM      128
#define BN      128
#define BK      32
#define KTILES  (HIDDEN / BK)   // 32

typedef __bf16 bf16;
typedef __attribute__((ext_vector_type(8))) __bf16 bf16x8;
typedef __attribute__((ext_vector_type(4))) __bf16 bf16x4;
typedef __attribute__((ext_vector_type(4))) float  f32x4;

__device__ __forceinline__ void async_ld16(const bf16* g, bf16* l) {
    __builtin_amdgcn_global_load_lds(
        (const __attribute__((address_space(1))) uint32_t*)g,
        (__attribute__((address_space(3))) uint32_t*)l,
        16, 0, 0);
}

__device__ __forceinline__ bf16x8 cvt8(f32x4 a, f32x4 b) {
    bf16x8 r;
    r[0] = (bf16)a[0]; r[1] = (bf16)a[1]; r[2] = (bf16)a[2]; r[3] = (bf16)a[3];
    r[4] = (bf16)b[0]; r[5] = (bf16)b[1]; r[6] = (bf16)b[2]; r[7] = (bf16)b[3];
    return r;
}

__global__ void convert_w_kernel(const float* __restrict__ W, bf16* __restrict__ Wb) {
    int i = (blockIdx.x * 256 + threadIdx.x) * 4;
    f32x4 v = *(const f32x4*)(W + i);
    bf16x4 o;
    o[0] = (bf16)v[0]; o[1] = (bf16)v[1]; o[2] = (bf16)v[2]; o[3] = (bf16)v[3];
    *(bf16x4*)(Wb + i) = o;
}

__global__ __launch_bounds__(256, 3)
void moa_gemm_kernel(const float* __restrict__ X, const bf16* __restrict__ Wb,
                     const float* __restrict__ bias, float* __restrict__ out) {
    __shared__ bf16 Asm[2][BM * BK];   // 2 x 8 KB
    __shared__ bf16 Bsm[2][BN * BK];   // 2 x 8 KB

    const int tid  = threadIdx.x;
    const int wave = tid >> 6;
    const int lane = tid & 63;

    // ---- XCD-aware remap: all 8 col-tiles of a row-panel share L%8 (=XCD)
    // and are dispatched within a span of 56 linear ids (lockstep sharing).
    const int L     = blockIdx.x;
    const int xcd   = L & 7;
    const int k     = L >> 3;
    const int col   = k & 7;
    const int panel = ((k >> 3) << 3) | xcd;
    const int tileM = panel * BM;
    const int tileN = col * BN;

    // ---- A staging: thread t -> linear 16B LDS slots t and t+256, gather
    // swizzle g' = g ^ (r&3) ^ ((r>>2)&3) applied on the global side.
    const int ar = tid >> 2;
    const int ag = (tid & 3) ^ (ar & 3) ^ ((ar >> 2) & 3);
    const float* aP0 = X + (size_t)(tileM + ar) * HIDDEN + ag * 8;
    const float* aP1 = aP0 + (size_t)64 * HIDDEN;

    // ---- B staging (async 16B, wave-linear LDS dst)
    const int br = lane >> 2;
    const int bg = (lane & 3) ^ (br & 3) ^ ((br >> 2) & 3);
    const bf16* bP = Wb + (size_t)(tileN + wave * 32 + br) * HIDDEN + bg * 8;

    // ---- fragment read map (16x16x32 bf16), matching the swizzle
    const int frow = lane & 15;
    const int fq   = lane >> 4;
    const int fko  = (fq ^ (frow & 3) ^ ((frow >> 2) & 3)) * 8;
    const int waveM = (wave >> 1) * 64;
    const int waveN = (wave & 1) * 64;

    f32x4 acc[4][4];
    #pragma unroll
    for (int i = 0; i < 4; ++i)
        #pragma unroll
        for (int j = 0; j < 4; ++j) acc[i][j] = f32x4{0.f, 0.f, 0.f, 0.f};

    // ---- prologue: stage tile 0 into buffer 0
    {
        async_ld16(bP,               &Bsm[0][wave * 1024]);
        async_ld16(bP + 16 * HIDDEN, &Bsm[0][wave * 1024 + 512]);
        f32x4 a0 = ((const f32x4*)aP0)[0];
        f32x4 a1 = ((const f32x4*)aP0)[1];
        f32x4 a2 = ((const f32x4*)aP1)[0];
        f32x4 a3 = ((const f32x4*)aP1)[1];
        *(bf16x8*)(&Asm[0][tid * 8])        = cvt8(a0, a1);
        *(bf16x8*)(&Asm[0][2048 + tid * 8]) = cvt8(a2, a3);
    }

    f32x4 apf0, apf1, apf2, apf3;
    for (int kt = 0; kt < KTILES; ++kt) {
        __syncthreads();  // tile kt visible (A ds_write + B async drained);
                          // all waves done reading the (kt+1)&1 buffers.
        const int nkt = kt + 1;
        if (nkt < KTILES) {
            // issue next tile's loads immediately after the barrier
            const bf16* bsrc = bP + nkt * BK;
            bf16* bdst = &Bsm[nkt & 1][wave * 1024];
            async_ld16(bsrc,               bdst);
            async_ld16(bsrc + 16 * HIDDEN, bdst + 512);
            const f32x4* s0 = (const f32x4*)(aP0 + nkt * BK);
            const f32x4* s1 = (const f32x4*)(aP1 + nkt * BK);
            apf0 = s0[0]; apf1 = s0[1];
            apf2 = s1[0]; apf3 = s1[1];
        }

        const bf16* Ab = &Asm[kt & 1][(waveM + frow) * BK + fko];
        const bf16* Bb = &Bsm[kt & 1][(waveN + frow) * BK + fko];
        bf16x8 aF[4], bF[4];
        #pragma unroll
        for (int mi = 0; mi < 4; ++mi) aF[mi] = *(const bf16x8*)(Ab + mi * 16 * BK);
        #pragma unroll
        for (int ni = 0; ni < 4; ++ni) bF[ni] = *(const bf16x8*)(Bb + ni * 16 * BK);
        #pragma unroll
        for (int mi = 0; mi < 4; ++mi)
            #pragma unroll
            for (int ni = 0; ni < 4; ++ni)
                acc[mi][ni] = __builtin_amdgcn_mfma_f32_16x16x32_bf16(
                    aF[mi], bF[ni], acc[mi][ni], 0, 0, 0);

        if (nkt < KTILES) {
            // cvt + stage next A tile (vmcnt wait lands here, a full MFMA
            // phase after issue)
            *(bf16x8*)(&Asm[nkt & 1][tid * 8])        = cvt8(apf0, apf1);
            *(bf16x8*)(&Asm[nkt & 1][2048 + tid * 8]) = cvt8(apf2, apf3);
        }
    }

    // ---- epilogue: C/D layout col=lane&15, row=(lane>>4)*4+r
    const int orow0 = tileM + waveM + (lane >> 4) * 4;
    const int ocol0 = tileN + waveN + (lane & 15);
    float bv[4];
    #pragma unroll
    for (int ni = 0; ni < 4; ++ni) bv[ni] = bias[ocol0 + ni * 16];
    #pragma unroll
    for (int mi = 0; mi < 4; ++mi) {
        #pragma unroll
        for (int r = 0; r < 4; ++r) {
            float* orow = out + (size_t)(orow0 + mi * 16 + r) * HIDDEN;
            #pragma unroll
            for (int ni = 0; ni < 4; ++ni)
                orow[ocol0 + ni * 16] = acc[mi][ni][r] + bv[ni];
        }
    }
}

extern "C" void kernel_launch(void* const* d_in, const int* in_sizes, int n_in,
                              void* d_out, int out_size, void* d_ws, size_t ws_size,
                              hipStream_t stream) {
    const float* x  = (const float*)d_in[0];
    const float* W  = (const float*)d_in[2];   // [8,1024,1024]; adaptor 0 first
    const float* b  = (const float*)d_in[3];   // [8,1024]
    float* out      = (float*)d_out;
    bf16*  Wb       = (bf16*)d_ws;

    convert_w_kernel<<<dim3(HIDDEN * HIDDEN / (256 * 4)), dim3(256), 0, stream>>>(W, Wb);

    moa_gemm_kernel<<<dim3((BATCH / BM) * (HIDDEN / BN)), dim3(256), 0, stream>>>(
        x, Wb, b, out);
}